// Round 4
// baseline (17592.726 us; speedup 1.0000x reference)
//
#include <hip/hip_runtime.h>

#define TT 128
#define BB 64
#define HH 2048
#define VV 10000
#define VP 10048

typedef __attribute__((ext_vector_type(8))) short s16x8;
typedef __attribute__((ext_vector_type(4))) float f32x4;

#define MFMA(a,b,c) __builtin_amdgcn_mfma_f32_16x16x32_bf16((a),(b),(c),0,0,0)

static __device__ __forceinline__ short f2bf(float x){
  unsigned u = __float_as_uint(x);
  u += 0x7fffu + ((u>>16)&1u);
  return (short)(u>>16);
}
static __device__ __forceinline__ float bf2f(short b){
  return __uint_as_float(((unsigned)(unsigned short)b)<<16);
}

// Swizzled fragment layout for an [N,K] matrix used as MFMA B-operand (or [M,K] as A):
//   idx = ((nt*KC + kc)*64 + lane)*8 + j,  row = nt*16+(lane&15), k = kc*32+(lane>>4)*8+j
// -> a wave's fragment load is 64 lanes x 16B contiguous.

// ---------- split W0 into x-part / h-part, hi/lo bf16, swizzled (KC=64 each) ----------
__global__ __launch_bounds__(256) void k_split_w0(
    const float* __restrict__ W0,
    short* __restrict__ WxHi, short* __restrict__ WxLo,
    short* __restrict__ WhHi, short* __restrict__ WhLo){
  int tid = blockIdx.x*256 + threadIdx.x;     // 2048*512 threads
  int row = tid >> 9;
  int c8  = (tid & 511) << 3;
  const float4* s = (const float4*)(W0 + (size_t)row*4096 + c8);
  float4 f0 = s[0], f1 = s[1];
  float v[8] = {f0.x,f0.y,f0.z,f0.w,f1.x,f1.y,f1.z,f1.w};
  short hs[8], lsv[8];
#pragma unroll
  for(int j=0;j<8;j++){ hs[j]=f2bf(v[j]); lsv[j]=f2bf(v[j]-bf2f(hs[j])); }
  int isH = (c8 >= 2048);
  int k = c8 - (isH ? 2048 : 0);
  short* dh = isH ? WhHi : WxHi;
  short* dl = isH ? WhLo : WxLo;
  int nt = row>>4, kc = k>>5, ln = (row&15) | (((k>>3)&3)<<4);
  size_t base = ((size_t)(nt*64 + kc)*64 + ln)*8;
  *(s16x8*)(dh+base) = *(s16x8*)hs;
  *(s16x8*)(dl+base) = *(s16x8*)lsv;
}

// ---------- split W1 (K=4096, KC=128) ----------
__global__ __launch_bounds__(256) void k_split_w1(
    const float* __restrict__ W1,
    short* __restrict__ WHi, short* __restrict__ WLo){
  int tid = blockIdx.x*256 + threadIdx.x;
  int row = tid >> 9;
  int c8  = (tid & 511) << 3;
  const float4* s = (const float4*)(W1 + (size_t)row*4096 + c8);
  float4 f0 = s[0], f1 = s[1];
  float v[8] = {f0.x,f0.y,f0.z,f0.w,f1.x,f1.y,f1.z,f1.w};
  short hs[8], lsv[8];
#pragma unroll
  for(int j=0;j<8;j++){ hs[j]=f2bf(v[j]); lsv[j]=f2bf(v[j]-bf2f(hs[j])); }
  int nt = row>>4, kc = c8>>5, ln = (row&15) | (((c8>>3)&3)<<4);
  size_t base = ((size_t)(nt*128 + kc)*64 + ln)*8;
  *(s16x8*)(WHi+base) = *(s16x8*)hs;
  *(s16x8*)(WLo+base) = *(s16x8*)lsv;
}

// ---------- Wout -> single bf16, swizzled, zero-padded to 10048 rows ----------
__global__ __launch_bounds__(256) void k_conv_wout(
    const float* __restrict__ Wout, short* __restrict__ Wo){
  int row = blockIdx.x;             // 0..10047
  int k = threadIdx.x << 3;
  short hs[8];
  if(row < VV){
    const float4* s = (const float4*)(Wout + (size_t)row*2048 + k);
    float4 f0 = s[0], f1 = s[1];
    float v[8] = {f0.x,f0.y,f0.z,f0.w,f1.x,f1.y,f1.z,f1.w};
#pragma unroll
    for(int j=0;j<8;j++) hs[j]=f2bf(v[j]);
  } else {
#pragma unroll
    for(int j=0;j<8;j++) hs[j]=0;
  }
  int nt = row>>4, kc = k>>5, ln = (row&15) | (((k>>3)&3)<<4);
  size_t base = ((size_t)(nt*64 + kc)*64 + ln)*8;
  *(s16x8*)(Wo+base) = *(s16x8*)hs;
}

// ---------- init h state from `hidden` (parity-1 buffers) + zero tickets ----------
__global__ __launch_bounds__(256) void k_init(
    const float* __restrict__ hid,
    short* __restrict__ h0Hi, short* __restrict__ h0Lo,
    short* __restrict__ h1Hi, short* __restrict__ h1Lo,
    int* __restrict__ tick){
  if(blockIdx.x==0 && threadIdx.x<32) tick[threadIdx.x] = 0;
  int tid = blockIdx.x*256 + threadIdx.x;   // 32768
  int l = tid >> 14;
  int r = tid & 16383;
  int m = r >> 8;
  int k = (r & 255) << 3;
  const float* s = hid + ((size_t)l*BB + m)*HH + k;
  float v[8];
#pragma unroll
  for(int j=0;j<8;j++) v[j]=s[j];
  short* dh = l ? h1Hi : h0Hi;
  short* dl = l ? h1Lo : h0Lo;
  short hs[8], lsv[8];
#pragma unroll
  for(int j=0;j<8;j++){ hs[j]=f2bf(v[j]); lsv[j]=f2bf(v[j]-bf2f(hs[j])); }
  int mt = m>>4, kc = k>>5, ln = (m&15) | (((k>>3)&3)<<4);
  size_t base = ((size_t)(mt*64 + kc)*64 + ln)*8;
  *(s16x8*)(dh+base) = *(s16x8*)hs;
  *(s16x8*)(dl+base) = *(s16x8*)lsv;
}

// ---------- Phase A: P0 = gather(emb)[8192,2048] @ Wx0^T + b0  (hi/lo 3-product) ----------
__global__ __launch_bounds__(256) void k_gemmA(
    const int* __restrict__ toks, const float* __restrict__ emb,
    const short* __restrict__ WxHi, const short* __restrict__ WxLo,
    const float* __restrict__ b0, float* __restrict__ P0){
  __shared__ short aHi[2][2048];
  __shared__ short aLo[2][2048];
  int bx = blockIdx.x, by = blockIdx.y;
  int tid = threadIdx.x, w = tid>>6, ln = tid&63;
  int srow = w*16 + (ln&15);
  int tok = toks[by*64 + srow];
  const float* rowp = emb + (size_t)tok*2048 + ((ln>>4)<<3);
  int nt = bx*4 + w;
  f32x4 acc[4] = {{0,0,0,0},{0,0,0,0},{0,0,0,0},{0,0,0,0}};
  for(int kc=0;kc<64;kc++){
    int p = kc&1;
    const float4* sp = (const float4*)(rowp + kc*32);
    float4 f0 = sp[0], f1 = sp[1];
    float v[8] = {f0.x,f0.y,f0.z,f0.w,f1.x,f1.y,f1.z,f1.w};
    short hs[8], lsv[8];
#pragma unroll
    for(int j=0;j<8;j++){ hs[j]=f2bf(v[j]); lsv[j]=f2bf(v[j]-bf2f(hs[j])); }
    *(s16x8*)&aHi[p][tid*8] = *(s16x8*)hs;
    *(s16x8*)&aLo[p][tid*8] = *(s16x8*)lsv;
    __syncthreads();
    size_t bidx = ((size_t)(nt*64 + kc)*64 + ln)*8;
    s16x8 bh = *(const s16x8*)(WxHi + bidx);
    s16x8 bl = *(const s16x8*)(WxLo + bidx);
#pragma unroll
    for(int mt=0;mt<4;mt++){
      s16x8 ah = *(const s16x8*)&aHi[p][(mt*64+ln)*8];
      s16x8 al = *(const s16x8*)&aLo[p][(mt*64+ln)*8];
      acc[mt] = MFMA(ah,bh,acc[mt]);
      acc[mt] = MFMA(al,bh,acc[mt]);
      acc[mt] = MFMA(ah,bl,acc[mt]);
    }
  }
  int nl = ln&15;
  int n = bx*64 + w*16 + nl;
  float bias = b0[n];
  int r0 = (ln>>4)*4;
#pragma unroll
  for(int mt=0;mt<4;mt++){
#pragma unroll
    for(int r=0;r<4;r++){
      int m = by*64 + mt*16 + r0 + r;
      P0[(size_t)m*HH + n] = acc[mt][r] + bias;
    }
  }
}

// ---------- per-step split-K kernel with ticket finalizer ----------
// 256 blocks x 512 threads. Blocks 0..127: layer0, (nt=bid>>3, ks=bid&7),
// K-slice of 256 (8 kc). Blocks 128..255: layer1, K-slice of 512 (16 kc).
// Each block stages its A-slice in LDS, computes a partial [64 x 128cols],
// stores fp32 partials, fences, barriers, then tickets. The 8th arriver per
// (layer,nt) group acquires, sums the 8 partials, applies bias/P0 + tanh,
// emits h-state. No spinning -> deadlock-free regardless of residency.
__global__ __launch_bounds__(512,2) void k_step(
    int t,
    const short* __restrict__ h0rH, const short* __restrict__ h0rL,  // h0(t-1)
    const short* __restrict__ h1rH, const short* __restrict__ h1rL,  // h1(t-2)
    const short* __restrict__ WhHi, const short* __restrict__ WhLo,
    const short* __restrict__ W1Hi, const short* __restrict__ W1Lo,
    const float* __restrict__ P0t, const float* __restrict__ b1,
    float* __restrict__ Pl0, float* __restrict__ Pl1,
    int* __restrict__ tick,
    short* __restrict__ h0wH, short* __restrict__ h0wL,              // h0(t)
    short* __restrict__ h1wH, short* __restrict__ h1wL,              // h1(t-1)
    short* __restrict__ H1t, float* __restrict__ fin){
  extern __shared__ short lds[];            // hi at 0, lo at +32768 shorts
  __shared__ int sflag;
  int bid = blockIdx.x;
  int isL1 = bid >= 128;
  if(isL1 ? (t==0) : (t==TT)) return;
  int idx = isL1 ? (bid-128) : bid;
  int nt = idx>>3, ks = idx&7;
  int tid = threadIdx.x, w = tid>>6, ln = tid&63;
  short* ldsH = lds;
  short* ldsL = lds + 32768;

  f32x4 acc[4] = {{0,0,0,0},{0,0,0,0},{0,0,0,0},{0,0,0,0}};

  if(isL1){
    // stage A-slice: 4 mt x 16 kc x 64 ln vec8 (64KB hi + 64KB lo)
    const short* AH; const short* AL; int kc0;
    if(ks<4){ AH=h0rH; AL=h0rL; kc0=ks*16; }
    else    { AH=h1rH; AL=h1rL; kc0=(ks-4)*16; }
#pragma unroll
    for(int i=0;i<8;i++){
      int li = i*512 + tid;                 // 0..4095
      int mt = li>>10, rem = li&1023, kcl = rem>>6, l2 = rem&63;
      size_t src = ((size_t)(mt*64 + kc0 + kcl)*64 + l2)*8;
      *(s16x8*)&ldsH[(size_t)li*8] = *(const s16x8*)(AH+src);
      *(s16x8*)&ldsL[(size_t)li*8] = *(const s16x8*)(AL+src);
    }
    __syncthreads();
    int ntW = nt*8 + w;
    size_t bb = ((size_t)(ntW*128 + ks*16)*64 + ln)*8;
    s16x8 bh0 = *(const s16x8*)(W1Hi + bb);
    s16x8 bl0 = *(const s16x8*)(W1Lo + bb);
    s16x8 bh1 = *(const s16x8*)(W1Hi + bb + 512);
    s16x8 bl1 = *(const s16x8*)(W1Lo + bb + 512);
#pragma unroll
    for(int i=0;i<16;i++){
      s16x8 bh = bh0, bl = bl0;
      bh0 = bh1; bl0 = bl1;
      if(i<14){
        bh1 = *(const s16x8*)(W1Hi + bb + (size_t)(i+2)*512);
        bl1 = *(const s16x8*)(W1Lo + bb + (size_t)(i+2)*512);
      }
#pragma unroll
      for(int mt=0;mt<4;mt++){
        s16x8 ah = *(const s16x8*)&ldsH[(size_t)(mt*1024 + i*64 + ln)*8];
        s16x8 al = *(const s16x8*)&ldsL[(size_t)(mt*1024 + i*64 + ln)*8];
        acc[mt] = MFMA(ah,bh,acc[mt]);
        acc[mt] = MFMA(al,bh,acc[mt]);
        acc[mt] = MFMA(ah,bl,acc[mt]);
      }
    }
  } else {
    // stage A-slice: 4 mt x 8 kc x 64 ln vec8 (32KB hi + 32KB lo)
    int kc0 = ks*8;
#pragma unroll
    for(int i=0;i<4;i++){
      int li = i*512 + tid;                 // 0..2047
      int mt = li>>9, rem = li&511, kcl = rem>>6, l2 = rem&63;
      size_t src = ((size_t)(mt*64 + kc0 + kcl)*64 + l2)*8;
      *(s16x8*)&ldsH[(size_t)li*8] = *(const s16x8*)(h0rH+src);
      *(s16x8*)&ldsL[(size_t)li*8] = *(const s16x8*)(h0rL+src);
    }
    __syncthreads();
    int ntW = nt*8 + w;
    size_t bb = ((size_t)(ntW*64 + ks*8)*64 + ln)*8;
    s16x8 bh0 = *(const s16x8*)(WhHi + bb);
    s16x8 bl0 = *(const s16x8*)(WhLo + bb);
    s16x8 bh1 = *(const s16x8*)(WhHi + bb + 512);
    s16x8 bl1 = *(const s16x8*)(WhLo + bb + 512);
#pragma unroll
    for(int i=0;i<8;i++){
      s16x8 bh = bh0, bl = bl0;
      bh0 = bh1; bl0 = bl1;
      if(i<6){
        bh1 = *(const s16x8*)(WhHi + bb + (size_t)(i+2)*512);
        bl1 = *(const s16x8*)(WhLo + bb + (size_t)(i+2)*512);
      }
#pragma unroll
      for(int mt=0;mt<4;mt++){
        s16x8 ah = *(const s16x8*)&ldsH[(size_t)(mt*512 + i*64 + ln)*8];
        s16x8 al = *(const s16x8*)&ldsL[(size_t)(mt*512 + i*64 + ln)*8];
        acc[mt] = MFMA(ah,bh,acc[mt]);
        acc[mt] = MFMA(al,bh,acc[mt]);
        acc[mt] = MFMA(ah,bl,acc[mt]);
      }
    }
  }

  // store partials: [nt][ks][w][mt][ln] f32x4
  f32x4* Pp = (f32x4*)(isL1 ? Pl1 : Pl0);
  size_t pbase = (size_t)(((nt*8 + ks)*8 + w)*4)*64 + ln;
#pragma unroll
  for(int mt=0;mt<4;mt++) Pp[pbase + (size_t)mt*64] = acc[mt];

  // Release protocol (race-free): every thread makes its partials visible
  // device-wide, then block-barrier so ALL waves' fences precede the ticket.
  __threadfence();
  __syncthreads();
  int g = (isL1?16:0) + nt;
  if(tid==0) sflag = atomicAdd(&tick[g], 1);
  __syncthreads();
  if(sflag != 7) return;

  // -------- finalizer (8th arriver): all partials complete & visible --------
  __threadfence();                          // acquire: invalidate stale lines
  f32x4 sum[4];
#pragma unroll
  for(int mt=0;mt<4;mt++) sum[mt] = acc[mt];
  for(int k2=0;k2<8;k2++){
    if(k2==ks) continue;
    size_t pb = (size_t)(((nt*8 + k2)*8 + w)*4)*64 + ln;
#pragma unroll
    for(int mt=0;mt<4;mt++) sum[mt] += Pp[pb + (size_t)mt*64];
  }
  int colb = nt*128 + w*16 + (ln&15);
  int rbase = (ln>>4)*4;
  int n = colb;
  int kcq = n>>5, lnc = ((n>>3)&3)<<4, j = n&7;
  float bias = isL1 ? b1[n] : 0.f;
#pragma unroll
  for(int mt=0;mt<4;mt++){
#pragma unroll
    for(int r=0;r<4;r++){
      int m = mt*16 + rbase + r;
      float v;
      if(!isL1) v = tanhf(sum[mt][r] + P0t[(size_t)m*HH + n]);
      else      v = tanhf(sum[mt][r] + bias);
      short hi = f2bf(v), lo = f2bf(v - bf2f(hi));
      size_t sidx = ((size_t)(mt*64 + kcq)*64 + ((m&15)|lnc))*8 + j;
      if(!isL1){
        h0wH[sidx] = hi; h0wL[sidx] = lo;
        if(t == TT-1) fin[(size_t)m*HH + n] = v;
      } else {
        h1wH[sidx] = hi; h1wL[sidx] = lo; H1t[sidx] = hi;
        if(t == TT) fin[(size_t)BB*HH + (size_t)m*HH + n] = v;
      }
    }
  }
  if(tid==0) atomicExch(&tick[g], 0);       // reset for next step's reuse
}

// ---------- Phase C: logits = H1[8192,2048] @ Wout^T + bout (barrier-free 64x64/wave) ----------
__global__ __launch_bounds__(256) void k_gemmC(
    const short* __restrict__ H1s, const short* __restrict__ Wo,
    const float* __restrict__ bout, float* __restrict__ outp){
  int bid = blockIdx.x;                 // 5024 = 8*628 blocks
  int swz = (bid & 7)*628 + (bid >> 3); // XCD-contiguous chunks
  int by = swz / 157;                   // M-panel (256 rows)
  int bx = swz - by*157;                // N-panel (64 cols)
  int tid = threadIdx.x, w = tid>>6, ln = tid&63;
  const short* Ab = H1s + (size_t)(by*16 + w*4)*32768 + ln*8;
  const short* Bb = Wo  + (size_t)(bx*4)*32768 + ln*8;
  f32x4 acc[4][4] = {};
  s16x8 a[4], b[4];
#pragma unroll
  for(int i=0;i<4;i++){
    a[i] = *(const s16x8*)(Ab + (size_t)i*32768);
    b[i] = *(const s16x8*)(Bb + (size_t)i*32768);
  }
  for(int kc=0;kc<64;kc++){
    s16x8 a2[4], b2[4];
    int kn = (kc+1<64)?(kc+1):63;
#pragma unroll
    for(int i=0;i<4;i++){
      a2[i] = *(const s16x8*)(Ab + (size_t)i*32768 + kn*512);
      b2[i] = *(const s16x8*)(Bb + (size_t)i*32768 + kn*512);
    }
#pragma unroll
    for(int i=0;i<4;i++)
#pragma unroll
      for(int j=0;j<4;j++)
        acc[i][j] = MFMA(a[i], b[j], acc[i][j]);
#pragma unroll
    for(int i=0;i<4;i++){ a[i]=a2[i]; b[i]=b2[i]; }
  }
  int nl = ln&15, r0 = (ln>>4)*4;
#pragma unroll
  for(int j=0;j<4;j++){
    int n = (bx*4+j)*16 + nl;
    if(n < VV){
      float bias = bout[n];
#pragma unroll
      for(int i=0;i<4;i++){
        int mb = (by*16 + w*4 + i)*16 + r0;
#pragma unroll
        for(int r=0;r<4;r++)
          outp[(size_t)(mb+r)*VV + n] = acc[i][j][r] + bias;
      }
    }
  }
}

extern "C" void kernel_launch(void* const* d_in, const int* in_sizes, int n_in,
                              void* d_out, int out_size, void* d_ws, size_t ws_size,
                              hipStream_t stream){
  const int*   toks = (const int*)d_in[0];
  const float* hid  = (const float*)d_in[1];
  const float* emb  = (const float*)d_in[2];
  const float* W0   = (const float*)d_in[3];
  const float* b0   = (const float*)d_in[4];
  const float* W1   = (const float*)d_in[5];
  const float* b1   = (const float*)d_in[6];
  const float* Wout = (const float*)d_in[7];
  const float* bout = (const float*)d_in[8];
  float* out = (float*)d_out;

  char* ws = (char*)d_ws;
  size_t off = 0;
  auto take = [&](size_t bytes)->void*{
    void* r = ws + off; off += (bytes + 255) & ~(size_t)255; return r; };

  short* WxHi = (short*)take((size_t)2048*2048*2);
  short* WxLo = (short*)take((size_t)2048*2048*2);
  short* WhHi = (short*)take((size_t)2048*2048*2);
  short* WhLo = (short*)take((size_t)2048*2048*2);
  short* W1Hi = (short*)take((size_t)2048*4096*2);
  short* W1Lo = (short*)take((size_t)2048*4096*2);
  short* Wo   = (short*)take((size_t)VP*2048*2);
  float* P0   = (float*)take((size_t)8192*2048*4);
  short* H1s  = (short*)take((size_t)8192*2048*2);
  float* Pl0  = (float*)take((size_t)16*8*8*4*64*4*4);   // 4 MB partials l0
  float* Pl1  = (float*)take((size_t)16*8*8*4*64*4*4);   // 4 MB partials l1
  int*   tick = (int*)take(32*sizeof(int));
  short *h0Hi[2], *h0Lo[2], *h1Hi[2], *h1Lo[2];
  for(int i=0;i<2;i++){
    h0Hi[i] = (short*)take((size_t)64*2048*2);
    h0Lo[i] = (short*)take((size_t)64*2048*2);
    h1Hi[i] = (short*)take((size_t)64*2048*2);
    h1Lo[i] = (short*)take((size_t)64*2048*2);
  }

  k_split_w0<<<4096,256,0,stream>>>(W0, WxHi,WxLo,WhHi,WhLo);
  k_split_w1<<<4096,256,0,stream>>>(W1, W1Hi,W1Lo);
  k_conv_wout<<<VP,256,0,stream>>>(Wout, Wo);
  // h0(-1)/h1(-1) live in parity-1 buffers
  k_init<<<128,256,0,stream>>>(hid, h0Hi[1],h0Lo[1], h1Hi[1],h1Lo[1], tick);
  k_gemmA<<<dim3(32,128),256,0,stream>>>(toks, emb, WxHi, WxLo, b0, P0);

  hipFuncSetAttribute(reinterpret_cast<const void*>(k_step),
                      hipFuncAttributeMaxDynamicSharedMemorySize, 131072);
  float* fin = out + (size_t)8192*VV;

  // K_t computes h0(t) [blocks 0..127] and h1(t-1) [blocks 128..255]; t=0..128.
  for(int t=0;t<=TT;t++){
    int pa = (t-1)&1;            // parity of t-1  (== 1 for t==0)
    int pc = t&1;                // parity of t    (== parity of t-2)
    int tp = (t>0) ? (t-1) : 0;  // H1s slot (unused at t==0)
    int tc = (t<TT) ? t : (TT-1);// P0 slot  (unused at t==TT)
    k_step<<<256,512,131072,stream>>>(t,
        h0Hi[pa],h0Lo[pa],          // h0(t-1)
        h1Hi[pc],h1Lo[pc],          // h1(t-2)
        WhHi,WhLo, W1Hi,W1Lo,
        P0 + (size_t)tc*64*2048, b1,
        Pl0, Pl1, tick,
        h0Hi[pc],h0Lo[pc],          // h0(t)
        h1Hi[pa],h1Lo[pa],          // h1(t-1)
        H1s + (size_t)tp*64*2048, fin);
  }

  k_gemmC<<<5024,256,0,stream>>>(H1s, Wo, bout, out);
}